// Round 7
// baseline (164.645 us; speedup 1.0000x reference)
//
#include <hip/hip_runtime.h>
#include <hip/hip_bf16.h>

#define T_ 64
#define B_ 8
#define H_ 128
#define NH_ 4
#define D_ 256
#define TB_ 512          // T_*B_
#define EPS_ 1e-5f

typedef short bf16x8 __attribute__((ext_vector_type(8)));
typedef float f32x4 __attribute__((ext_vector_type(4)));

__device__ __forceinline__ float silu_(float x){ return x / (1.0f + __expf(-x)); }
__device__ __forceinline__ float sigm_(float x){ return 1.0f / (1.0f + __expf(-x)); }
__device__ __forceinline__ unsigned short tobf_(float f){
  unsigned u = __float_as_uint(f);
  u += 0x7FFF + ((u >> 16) & 1);          // round-to-nearest-even
  return (unsigned short)(u >> 16);
}
// A-fragment-linear address, element (m,k) of [M x 256] bf16 matrix (K=256)
__device__ __forceinline__ int afrag_(int m, int k){
  return (((m >> 4)*8 + (k >> 5))*64 + ((k >> 3)&3)*16 + (m & 15))*8 + (k & 7);
}

// ---------------- K1: weight conversions only ----------------
// 0..639: Wq/Wk/Ws/Wv/Wo B-frag | 640..671: Wup1/2 B-frag K=128
// 672..799: Wpoll B-frag K=1024 | 800..815: Wdown B-frag K=256
__global__ __launch_bounds__(256) void k_prep(
    const float* __restrict__ Wq, const float* __restrict__ Wk, const float* __restrict__ Ws,
    const float* __restrict__ Wv, const float* __restrict__ Wo,
    const float* __restrict__ Wup1, const float* __restrict__ Wup2,
    const float* __restrict__ Wp, const float* __restrict__ Wd,
    unsigned short* __restrict__ Wqt, unsigned short* __restrict__ Wkt,
    unsigned short* __restrict__ Wst, unsigned short* __restrict__ Wvt,
    unsigned short* __restrict__ Wot,
    unsigned short* __restrict__ Wu1t, unsigned short* __restrict__ Wu2t,
    unsigned short* __restrict__ Wpt, unsigned short* __restrict__ Wdt){
  int bid = blockIdx.x;
  int tid = threadIdx.x;
  if (bid < 640){
    int sub = bid & 31;
    int h   = (bid >> 5) & 3;
    int mat = bid >> 7;
    const float* Win; unsigned short* Wout;
    switch (mat){
      case 0: Win = Wq; Wout = Wqt; break;
      case 1: Win = Wk; Wout = Wkt; break;
      case 2: Win = Ws; Wout = Wst; break;
      case 3: Win = Wv; Wout = Wvt; break;
      default: Win = Wo; Wout = Wot; break;
    }
    Win  += h * (D_*D_);
    Wout += h * (D_*D_);
    int gid = sub*256 + tid;
    int combo = gid >> 6;                // nt*8 + kb
    int l = gid & 63;
    int lm = l & 15, lq = l >> 4;
    int nt = combo >> 3, kb = combo & 7;
    int n = nt*16 + lm;
    int k0 = kb*32 + lq*8;
    bf16x8 v;
    #pragma unroll
    for (int j = 0; j < 8; j++) v[j] = (short)tobf_(Win[(k0+j)*D_ + n]);
    *(bf16x8*)(Wout + (combo*64 + l)*8) = v;
  } else if (bid < 672){
    int idx = bid - 640;
    const float* Win = (idx < 16) ? Wup1 : Wup2;
    unsigned short* Wout = (idx < 16) ? Wu1t : Wu2t;
    int sub = idx & 15;
    int gid = sub*256 + tid;             // [0,4096)
    int combo = gid >> 6;                // nt*4 + kb  (K=128)
    int l = gid & 63;
    int lm = l & 15, lq = l >> 4;
    int nt = combo >> 2, kb = combo & 3;
    int n = nt*16 + lm;
    int k0 = kb*32 + lq*8;
    bf16x8 v;
    #pragma unroll
    for (int j = 0; j < 8; j++) v[j] = (short)tobf_(Win[(k0+j)*D_ + n]);
    *(bf16x8*)(Wout + (combo*64 + l)*8) = v;
  } else if (bid < 800){
    // Wpoll [1024 x 256] -> B-frag K=1024
    int gid = (bid - 672)*256 + tid;     // [0, 32768)
    int combo = gid >> 6;                // nt*32 + kb
    int l = gid & 63;
    int lm = l & 15, lq = l >> 4;
    int nt = combo >> 5, kb = combo & 31;
    int n = nt*16 + lm;
    int k0 = kb*32 + lq*8;
    bf16x8 v;
    #pragma unroll
    for (int j = 0; j < 8; j++) v[j] = (short)tobf_(Wp[(k0+j)*D_ + n]);
    *(bf16x8*)(Wpt + (combo*64 + l)*8) = v;
  } else {
    // Wdown [256 x 128] -> B-frag K=256
    int gid = (bid - 800)*256 + tid;     // [0, 4096)
    int combo = gid >> 6;                // nt*8 + kb
    int l = gid & 63;
    int lm = l & 15, lq = l >> 4;
    int nt = combo >> 3, kb = combo & 7;
    int n = nt*16 + lm;
    int k0 = kb*32 + lq*8;
    bf16x8 v;
    #pragma unroll
    for (int j = 0; j < 8; j++) v[j] = (short)tobf_(Wd[(k0+j)*H_ + n]);
    *(bf16x8*)(Wdt + (combo*64 + l)*8) = v;
  }
}

// ---------------- K2: bn1 (fused) + up-proj MFMA + conv/gates (mat0) / trig (mat1) ----------------
// grid 64: mat = bid>>5, rt = bid&31 (16 rows = 2 t)
__global__ __launch_bounds__(256) void k_upcg(
    const float* __restrict__ x, const float* __restrict__ bn1s, const float* __restrict__ bn1b,
    const unsigned short* __restrict__ Wu1t, const unsigned short* __restrict__ Wu2t,
    const float* __restrict__ bup1, const float* __restrict__ bup2,
    const float* __restrict__ ck, const float* __restrict__ cb,
    const float* __restrict__ Wi, const float* __restrict__ bi,
    const float* __restrict__ Wf, const float* __restrict__ bfv,
    unsigned short* __restrict__ xinb, unsigned short* __restrict__ qkb,
    float* __restrict__ trig, float* __restrict__ itb, float* __restrict__ ftb){
  __shared__ float xs[16][257];
  __shared__ unsigned short uf[2048];     // u bf16 A-frag (16 x 128), 4 KB
  int bid = blockIdx.x;
  int mat = bid >> 5, rt = bid & 31;
  int tid = threadIdx.x;
  int w = tid >> 6, l = tid & 63, lm = l & 15, lq = l >> 4;
  // ---- bn1 in-block: thread = (t_local, hf); rows rt*16+m, m = t_local*8+b ----
  {
    int tl = tid >> 7, hf = tid & 127;
    int t = rt*2 + tl;
    const float* xp = x + t*(B_*H_) + hf;
    float v0[8]; float mu = 0.f;
    #pragma unroll
    for (int b = 0; b < 8; b++){ v0[b] = xp[b*H_]; mu += v0[b]; }
    mu *= 0.125f;
    float var = 0.f;
    #pragma unroll
    for (int b = 0; b < 8; b++){ float dd = v0[b]-mu; var += dd*dd; }
    var *= 0.125f;
    float sc = (1.0f/sqrtf(var + EPS_)) * bn1s[hf];
    float bs = bn1b[hf];
    // A-frag (K=128): addr = ((k>>5)*64 + ((k>>3)&3)*16 + m)*8 + (k&7)
    int base = ((hf >> 5)*64 + ((hf >> 3)&3)*16)*8 + (hf & 7);
    #pragma unroll
    for (int b = 0; b < 8; b++){
      int m = tl*8 + b;
      uf[base + m*8] = tobf_((v0[b]-mu)*sc + bs);
    }
  }
  __syncthreads();
  const unsigned short* Bt = (mat == 0) ? Wu1t : Wu2t;
  f32x4 acc[4];
  #pragma unroll
  for (int nt = 0; nt < 4; nt++) acc[nt] = (f32x4){0.f,0.f,0.f,0.f};
  const unsigned short* Bp = Bt + l*8;
  #pragma unroll
  for (int kb = 0; kb < 4; kb++){
    bf16x8 a = *(const bf16x8*)(uf + (kb*64 + l)*8);
    #pragma unroll
    for (int nt = 0; nt < 4; nt++){
      bf16x8 bfr = *(const bf16x8*)(Bp + (((w*4+nt)*4 + kb) << 9));
      acc[nt] = __builtin_amdgcn_mfma_f32_16x16x32_bf16(a, bfr, acc[nt], 0, 0, 0);
    }
  }
  const float* bias = (mat == 0) ? bup1 : bup2;
  #pragma unroll
  for (int nt = 0; nt < 4; nt++){
    #pragma unroll
    for (int r = 0; r < 4; r++){
      int m = lq*4 + r;
      int row = rt*16 + m;
      int e = w*64 + nt*16 + lm;
      float vv = acc[nt][r] + bias[e];
      if (mat == 1){
        trig[row*D_ + e] = silu_(vv);
      } else {
        xinb[afrag_(row, e)] = tobf_(vv);
        xs[m][e] = vv;
      }
    }
  }
  if (mat == 0){
    __syncthreads();
    int d = tid;
    #pragma unroll 4
    for (int m = 0; m < 16; m++){
      float x0  = xs[m][d];
      float xm1 = (d >= 1)   ? xs[m][d-1] : 0.f;
      float xp1 = (d <= 254) ? xs[m][d+1] : 0.f;
      float xp2 = (d <= 253) ? xs[m][d+2] : 0.f;
      int rowg = rt*16 + m;
      int fa = afrag_(rowg, d);
      #pragma unroll
      for (int h = 0; h < NH_; h++){
        float a2 = cb[h];
        a2 = fmaf(xm1, ck[0*NH_+h], a2);
        a2 = fmaf(x0,  ck[1*NH_+h], a2);
        a2 = fmaf(xp1, ck[2*NH_+h], a2);
        a2 = fmaf(xp2, ck[3*NH_+h], a2);
        qkb[h*(TB_*D_) + fa] = tobf_(silu_(a2));
      }
    }
    int dot = tid >> 2, l4 = tid & 3;
    int h = dot >> 4, m = dot & 15;
    float ai = 0.f, af = 0.f;
    const float* wi = Wi + h*D_;
    const float* wf = Wf + h*D_;
    #pragma unroll 8
    for (int jj = 0; jj < 64; jj++){
      int k = l4*64 + jj;
      float xv = xs[m][k];
      ai = fmaf(xv, wi[k], ai);
      af = fmaf(xv, wf[k], af);
    }
    ai += __shfl_down(ai, 1); af += __shfl_down(af, 1);
    ai += __shfl_down(ai, 2); af += __shfl_down(af, 2);
    if (l4 == 0){
      int rowg = rt*16 + m;
      int t = rowg >> 3, b = rowg & 7;
      itb[(h*B_ + b)*T_ + t] = ai + bi[h];
      ftb[(h*B_ + b)*T_ + t] = af + bfv[h];
    }
  }
}

// ---------------- K3: per-head 5-matmul MFMA GEMM; frag-layout epilogues for attn ----------------
__global__ __launch_bounds__(256) void k_gemm5(
    const unsigned short* __restrict__ qkb, const unsigned short* __restrict__ xinb,
    const unsigned short* __restrict__ Wqt, const unsigned short* __restrict__ Wkt,
    const unsigned short* __restrict__ Wst, const unsigned short* __restrict__ Wvt,
    const unsigned short* __restrict__ Wot,
    const float* __restrict__ bq, const float* __restrict__ bk, const float* __restrict__ bsk,
    const float* __restrict__ bv, const float* __restrict__ bo,
    unsigned short* __restrict__ qob, unsigned short* __restrict__ kob,
    unsigned short* __restrict__ vot,
    float* __restrict__ hb, float* __restrict__ og){
  int bid = blockIdx.x;
  int rt  = bid & 15;
  int h   = (bid >> 4) & 3;
  int mat = bid >> 6;                    // 0=q 1=k 2=skip 3=v 4=og
  int tid = threadIdx.x;
  int w = tid >> 6, l = tid & 63;
  int lm = l & 15, lq = l >> 4;
  int r0 = rt * 32;
  const unsigned short* A = (mat < 3) ? (qkb + h*(TB_*D_)) : xinb;
  const unsigned short* Bt;
  const float* bias;
  switch (mat){
    case 0: Bt = Wqt; bias = bq;  break;
    case 1: Bt = Wkt; bias = bk;  break;
    case 2: Bt = Wst; bias = bsk; break;
    case 3: Bt = Wvt; bias = bv;  break;
    default: Bt = Wot; bias = bo; break;
  }
  Bt += h*(D_*D_);
  f32x4 acc[2][4];
  #pragma unroll
  for (int mt = 0; mt < 2; mt++)
    #pragma unroll
    for (int nt = 0; nt < 4; nt++) acc[mt][nt] = (f32x4){0.f,0.f,0.f,0.f};
  const unsigned short* Ap = A + l*8;
  const unsigned short* Bp = Bt + l*8;
  #pragma unroll
  for (int kc = 0; kc < 8; kc++){
    bf16x8 a0 = *(const bf16x8*)(Ap + ((rt*16      + kc) << 9));
    bf16x8 a1 = *(const bf16x8*)(Ap + ((rt*16 + 8  + kc) << 9));
    bf16x8 b0 = *(const bf16x8*)(Bp + (((w*4+0)*8 + kc) << 9));
    bf16x8 b1 = *(const bf16x8*)(Bp + (((w*4+1)*8 + kc) << 9));
    bf16x8 b2 = *(const bf16x8*)(Bp + (((w*4+2)*8 + kc) << 9));
    bf16x8 b3 = *(const bf16x8*)(Bp + (((w*4+3)*8 + kc) << 9));
    acc[0][0] = __builtin_amdgcn_mfma_f32_16x16x32_bf16(a0, b0, acc[0][0], 0, 0, 0);
    acc[0][1] = __builtin_amdgcn_mfma_f32_16x16x32_bf16(a0, b1, acc[0][1], 0, 0, 0);
    acc[0][2] = __builtin_amdgcn_mfma_f32_16x16x32_bf16(a0, b2, acc[0][2], 0, 0, 0);
    acc[0][3] = __builtin_amdgcn_mfma_f32_16x16x32_bf16(a0, b3, acc[0][3], 0, 0, 0);
    acc[1][0] = __builtin_amdgcn_mfma_f32_16x16x32_bf16(a1, b0, acc[1][0], 0, 0, 0);
    acc[1][1] = __builtin_amdgcn_mfma_f32_16x16x32_bf16(a1, b1, acc[1][1], 0, 0, 0);
    acc[1][2] = __builtin_amdgcn_mfma_f32_16x16x32_bf16(a1, b2, acc[1][2], 0, 0, 0);
    acc[1][3] = __builtin_amdgcn_mfma_f32_16x16x32_bf16(a1, b3, acc[1][3], 0, 0, 0);
  }
  float bval[4];
  #pragma unroll
  for (int nt = 0; nt < 4; nt++) bval[nt] = bias[h*D_ + w*64 + nt*16 + lm];
  #pragma unroll
  for (int mt = 0; mt < 2; mt++){
    #pragma unroll
    for (int r = 0; r < 4; r++){
      int row = r0 + mt*16 + lq*4 + r;
      int t = row >> 3, b = row & 7;
      #pragma unroll
      for (int nt = 0; nt < 4; nt++){
        int e = w*64 + nt*16 + lm;
        float vv = acc[mt][nt][r] + bval[nt];
        if (mat <= 1){
          if (mat == 1) vv *= 0.0625f;
          unsigned short* ob = (mat == 0) ? qob : kob;
          int mt2 = t >> 4, kb2 = e >> 5;
          int lane2 = ((e >> 3)&3)*16 + (t & 15);
          ob[(h*B_ + b)*16384 + ((mt2*8 + kb2)*64 + lane2)*8 + (e & 7)] = tobf_(vv);
        } else if (mat == 3){
          int nt3 = e >> 4, kb3 = t >> 5;
          int lane3 = ((t >> 3)&3)*16 + lm;
          vot[(h*B_ + b)*16384 + ((nt3*2 + kb3)*64 + lane3)*8 + (t & 7)] = tobf_(vv);
        } else {
          int obase = (((t*NH_ + h)*B_ + b) << 8) + e;
          if (mat == 4) og[obase] = sigm_(vv);
          else          hb[obase] = vv;        // skip term
        }
      }
    }
  }
}

// ---------------- K4: MFMA attention with fused gate scan ----------------
__global__ __launch_bounds__(256) void k_attn2(
    const unsigned short* __restrict__ qob, const unsigned short* __restrict__ kob,
    const unsigned short* __restrict__ vot, const float* __restrict__ og,
    const float* __restrict__ itb, const float* __restrict__ ftb,
    float* __restrict__ hb){
  __shared__ unsigned short Pf[1024];
  __shared__ float partial[4][16];
  __shared__ float scal[16];
  int bid = blockIdx.x;
  int hbx = bid >> 2, tq = bid & 3;
  int h = hbx >> 3, b = hbx & 7;
  int tid = threadIdx.x;
  int w = tid >> 6, l = tid & 63, lm = l & 15, lq = l >> 4;
  float F  = ftb[hbx*T_ + l];
  float it = itb[hbx*T_ + l];
  #pragma unroll
  for (int off = 1; off < 64; off <<= 1){
    float v2 = __shfl_up(F, off);
    if (l >= off) F += v2;
  }
  float ct = it - F;
  float G = ct;
  #pragma unroll
  for (int off = 1; off < 64; off <<= 1){
    float v2 = __shfl_up(G, off);
    if (l >= off) G = fmaxf(G, v2);
  }
  float rb = -fmaxf(0.f, G);
  const unsigned short* Aq = qob + hbx*16384 + l*8;
  const unsigned short* Bk = kob + hbx*16384 + l*8;
  f32x4 accs = (f32x4){0.f,0.f,0.f,0.f};
  #pragma unroll
  for (int kc = 0; kc < 8; kc++){
    bf16x8 a  = *(const bf16x8*)(Aq + ((tq*8 + kc) << 9));
    bf16x8 bb = *(const bf16x8*)(Bk + ((w*8  + kc) << 9));
    accs = __builtin_amdgcn_mfma_f32_16x16x32_bf16(a, bb, accs, 0, 0, 0);
  }
  int s = w*16 + lm;
  float ct_s = __shfl(ct, s);
  float p[4], ps[4];
  #pragma unroll
  for (int r = 0; r < 4; r++){
    int t = tq*16 + lq*4 + r;
    float rb_t = __shfl(rb, t);
    float pv = (s <= t) ? __expf(ct_s + rb_t) * accs[r] : 0.f;
    p[r] = pv; ps[r] = pv;
  }
  #pragma unroll
  for (int off = 1; off < 16; off <<= 1){
    #pragma unroll
    for (int r = 0; r < 4; r++) ps[r] += __shfl_xor(ps[r], off);
  }
  if (lm == 0){
    #pragma unroll
    for (int r = 0; r < 4; r++) partial[w][lq*4 + r] = ps[r];
  }
  {
    int kbP = w >> 1;
    int laneP = ((w*2 + (lm >> 3)) & 3)*16;
    int jP = lm & 7;
    #pragma unroll
    for (int r = 0; r < 4; r++){
      int m = lq*4 + r;
      Pf[(kbP*64 + laneP + m)*8 + jP] = tobf_(p[r]);
    }
  }
  __syncthreads();
  if (tid < 16){
    float sum = partial[0][tid] + partial[1][tid] + partial[2][tid] + partial[3][tid];
    scal[tid] = 1.0f / fmaxf(fabsf(sum), 1.0f);
  }
  bf16x8 pa0 = *(const bf16x8*)(Pf + l*8);
  bf16x8 pa1 = *(const bf16x8*)(Pf + 512 + l*8);
  const unsigned short* Bv = vot + hbx*16384 + l*8;
  f32x4 acco[4];
  #pragma unroll
  for (int nt = 0; nt < 4; nt++) acco[nt] = (f32x4){0.f,0.f,0.f,0.f};
  #pragma unroll
  for (int nt = 0; nt < 4; nt++){
    int nt3 = w*4 + nt;
    bf16x8 b0 = *(const bf16x8*)(Bv + (((nt3*2 + 0)) << 9));
    bf16x8 b1 = *(const bf16x8*)(Bv + (((nt3*2 + 1)) << 9));
    acco[nt] = __builtin_amdgcn_mfma_f32_16x16x32_bf16(pa0, b0, acco[nt], 0, 0, 0);
    acco[nt] = __builtin_amdgcn_mfma_f32_16x16x32_bf16(pa1, b1, acco[nt], 0, 0, 0);
  }
  __syncthreads();
  #pragma unroll
  for (int nt = 0; nt < 4; nt++){
    #pragma unroll
    for (int r = 0; r < 4; r++){
      int tl = lq*4 + r;
      int t = tq*16 + tl;
      int e = (w*4 + nt)*16 + lm;
      int idx = (((t*NH_ + h)*B_ + b) << 8) + e;
      hb[idx] += og[idx] * acco[nt][r] * scal[tl];
    }
  }
}

// ---------------- K5: fused bn2 + poll (K=1024, *trig) + down (K=256, +x) ----------------
// grid 16 (32 rows = 4 t), block 512 = 8 waves. bn2 per-thread (owns full (t,d) column).
__global__ __launch_bounds__(512) void k_tail3(
    const float* __restrict__ hbuf, const float* __restrict__ bn2s, const float* __restrict__ bn2b,
    const unsigned short* __restrict__ Wpt, const float* __restrict__ bp,
    const float* __restrict__ trig,
    const unsigned short* __restrict__ Wdt, const float* __restrict__ bd,
    const float* __restrict__ x, float* __restrict__ y){
  __shared__ unsigned short Af[16384];   // half-K A frags (32 x 512), 32 KB
  __shared__ unsigned short zf[8192];    // z bf16 A-frag (32 x 256), 16 KB
  int rt = blockIdx.x;
  int tid = threadIdx.x;
  int w = tid >> 6, l = tid & 63, lm = l & 15, lq = l >> 4;
  // bn2: each thread owns 2 (t_local,d) pairs; values+scale stay in registers
  float v[2][32], nmu[2], nsc[2], nbs[2];
  #pragma unroll
  for (int p = 0; p < 2; p++){
    int pair = tid + p*512;              // 0..1023
    int tl = pair >> 8, d = pair & 255;
    int t = rt*4 + tl;
    const float* hp = hbuf + (t*NH_*B_)*D_ + d;
    float mu = 0.f;
    #pragma unroll
    for (int i = 0; i < 32; i++){ v[p][i] = hp[i*D_]; mu += v[p][i]; }
    mu *= (1.0f/32.0f);
    float var = 0.f;
    #pragma unroll
    for (int i = 0; i < 32; i++){ float dd = v[p][i]-mu; var += dd*dd; }
    var *= (1.0f/32.0f);
    nmu[p] = mu;
    nsc[p] = (1.0f/sqrtf(var + EPS_)) * bn2s[d];
    nbs[p] = bn2b[d];
  }
  f32x4 acc[2][2];
  #pragma unroll
  for (int mt = 0; mt < 2; mt++)
    #pragma unroll
    for (int nt = 0; nt < 2; nt++) acc[mt][nt] = (f32x4){0.f,0.f,0.f,0.f};
  const unsigned short* Bp = Wpt + l*8;
  // two K-halves: half hf covers h in {2hf, 2hf+1} (k = h*256+d)
  for (int hf = 0; hf < 2; hf++){
    __syncthreads();
    // fill Af: i = h*8+b; local row m = tl*8+b; kh = (h - 2*hf)*256 + d
    #pragma unroll
    for (int p = 0; p < 2; p++){
      int pair = tid + p*512;
      int tl = pair >> 8, d = pair & 255;
      #pragma unroll
      for (int hh = 0; hh < 2; hh++){
        int i0 = (hf*2 + hh)*8;
        int kh = hh*256 + d;
        int abase = ((kh >> 5)*64 + ((kh >> 3)&3)*16)*8 + (kh & 7);
        #pragma unroll
        for (int b = 0; b < 8; b++){
          int m = tl*8 + b;
          float nv = (v[p][i0+b]-nmu[p])*nsc[p] + nbs[p];
          // A-frag local (M=32, K=512): (((m>>4)*16 + (kh>>5))*64 + lane)*8 + j
          Af[(((m >> 4)*16) * 64)*8 + abase + (m & 15)*8 + (((m>>4)*0))] = 0; // placeholder avoided below
        }
      }
    }
    // NOTE: the write above is replaced by the correct loop below (kept single write path)
    __syncthreads();
    __syncthreads();
  }
  // --- correct implementation (the loop above is dead; see k_tail3_impl) ---
}

// real tail implementation (clean)
__global__ __launch_bounds__(512) void k_tail3b(
    const float* __restrict__ hbuf, const float* __restrict__ bn2s, const float* __restrict__ bn2b,
    const unsigned short* __restrict__ Wpt, const float* __restrict__ bp,
    const float* __restrict__ trig,
    const unsigned short* __restrict__ Wdt, const float* __restrict__ bd,
    const float* __restrict__ x, float* __restrict__ y){
  __shared__ unsigned short Af[16384];   // half-K A frags (32 x 512), 32 KB
  __shared__ unsigned short zf[8192];    // z bf16 A-frag (32 x 256), 16 KB
  int rt = blockIdx.x;
  int tid = threadIdx.x;
  int w = tid >> 6, l = tid & 63, lm = l & 15, lq = l >> 4;
  float v[2][32], nmu[2], nsc[2], nbs[2];
  #pragma unroll
  for (int p = 0; p < 2; p++){
    int pair = tid + p*512;
    int tl = pair >> 8, d = pair & 255;
    int t = rt*4 + tl;
    const float* hp = hbuf + (t*NH_*B_)*D_ + d;
    float mu = 0.f;
    #pragma unroll
    for (int i = 0; i < 32; i++){ v[p][i] = hp[i*D_]; mu += v[p][i]; }
    mu *= (1.0f/32.0f);
    float var = 0.f;
    #pragma unroll
    for (int i = 0; i < 32; i++){ float dd = v[p][i]-mu; var += dd*dd; }
    var *= (1.0f/32.0f);
    nmu[p] = mu;
    nsc[p] = (1.0f/sqrtf(var + EPS_)) * bn2s[d];
    nbs[p] = bn2b[d];
  }
  f32x4 acc[2][2];
  #pragma unroll
  for (int mt = 0; mt < 2; mt++)
    #pragma unroll
    for (int nt = 0; nt < 2; nt++) acc[mt][nt] = (f32x4){0.f,0.f,0.f,0.f};
  const unsigned short* Bp = Wpt + l*8;
  for (int hf = 0; hf < 2; hf++){
    __syncthreads();                      // protect Af reuse across halves
    #pragma unroll
    for (int p = 0; p < 2; p++){
      int pair = tid + p*512;
      int tl = pair >> 8, d = pair & 255;
      #pragma unroll
      for (int hh = 0; hh < 2; hh++){
        int i0 = (hf*2 + hh)*8;
        int kh = hh*256 + d;              // k_local in [0,512)
        #pragma unroll
        for (int b = 0; b < 8; b++){
          int m = tl*8 + b;
          float nv = (v[p][i0+b]-nmu[p])*nsc[p] + nbs[p];
          // A-frag local (M=32, K=512): (((m>>4)*16 + (kh>>5))*64 + ((kh>>3)&3)*16 + (m&15))*8 + (kh&7)
          Af[(((m >> 4)*16 + (kh >> 5))*64 + ((kh >> 3)&3)*16 + (m & 15))*8 + (kh & 7)] = tobf_(nv);
        }
      }
    }
    __syncthreads();
    #pragma unroll 4
    for (int kc = 0; kc < 16; kc++){
      bf16x8 a0 = *(const bf16x8*)(Af + ((0*16 + kc)*64 + l)*8);
      bf16x8 a1 = *(const bf16x8*)(Af + ((1*16 + kc)*64 + l)*8);
      bf16x8 b0 = *(const bf16x8*)(Bp + (((w*2+0)*32 + hf*16 + kc) << 9));
      bf16x8 b1 = *(const bf16x8*)(Bp + (((w*2+1)*32 + hf*16 + kc) << 9));
      acc[0][0] = __builtin_amdgcn_mfma_f32_16x16x32_bf16(a0, b0, acc[0][0], 0, 0, 0);
      acc[0][1] = __builtin_amdgcn_mfma_f32_16x16x32_bf16(a0, b1, acc[0][1], 0, 0, 0);
      acc[1][0] = __builtin_amdgcn_mfma_f32_16x16x32_bf16(a1, b0, acc[1][0], 0, 0, 0);
      acc[1][1] = __builtin_amdgcn_mfma_f32_16x16x32_bf16(a1, b1, acc[1][1], 0, 0, 0);
    }
  }
  __syncthreads();
  #pragma unroll
  for (int mt = 0; mt < 2; mt++){
    #pragma unroll
    for (int nt = 0; nt < 2; nt++){
      int e = w*32 + nt*16 + lm;
      float bpe = bp[e];
      #pragma unroll
      for (int r = 0; r < 4; r++){
        int ml = mt*16 + lq*4 + r;
        int row = rt*32 + ml;
        float z = (acc[mt][nt][r] + bpe) * trig[row*D_ + e];
        zf[afrag_(ml, e)] = tobf_(z);
      }
    }
  }
  __syncthreads();
  f32x4 acc2[2];
  acc2[0] = (f32x4){0.f,0.f,0.f,0.f};
  acc2[1] = (f32x4){0.f,0.f,0.f,0.f};
  const unsigned short* Bdp = Wdt + l*8;
  #pragma unroll
  for (int kc = 0; kc < 8; kc++){
    bf16x8 a0 = *(const bf16x8*)(zf + ((0*8 + kc) << 9) + l*8);
    bf16x8 a1 = *(const bf16x8*)(zf + ((1*8 + kc) << 9) + l*8);
    bf16x8 bb = *(const bf16x8*)(Bdp + ((w*8 + kc) << 9));
    acc2[0] = __builtin_amdgcn_mfma_f32_16x16x32_bf16(a0, bb, acc2[0], 0, 0, 0);
    acc2[1] = __builtin_amdgcn_mfma_f32_16x16x32_bf16(a1, bb, acc2[1], 0, 0, 0);
  }
  int hh = w*16 + lm;
  float bde = bd[hh];
  #pragma unroll
  for (int mt = 0; mt < 2; mt++){
    #pragma unroll
    for (int r = 0; r < 4; r++){
      int row = rt*32 + mt*16 + lq*4 + r;
      y[row*H_ + hh] = acc2[mt][r] + bde + x[row*H_ + hh];
    }
  }
}

extern "C" void kernel_launch(void* const* d_in, const int* in_sizes, int n_in,
                              void* d_out, int out_size, void* d_ws, size_t ws_size,
                              hipStream_t stream){
  const float* x     = (const float*)d_in[0];
  const float* Wq    = (const float*)d_in[1];
  const float* bq    = (const float*)d_in[2];
  const float* Wk    = (const float*)d_in[3];
  const float* bk    = (const float*)d_in[4];
  const float* Wv    = (const float*)d_in[5];
  const float* bv    = (const float*)d_in[6];
  const float* ck    = (const float*)d_in[7];
  const float* cb    = (const float*)d_in[8];
  const float* Wi    = (const float*)d_in[9];
  const float* bi    = (const float*)d_in[10];
  const float* Wf    = (const float*)d_in[11];
  const float* bf    = (const float*)d_in[12];
  const float* Wo    = (const float*)d_in[13];
  const float* bo    = (const float*)d_in[14];
  const float* Wsk   = (const float*)d_in[15];
  const float* bsk   = (const float*)d_in[16];
  const float* bn1s  = (const float*)d_in[17];
  const float* bn1b  = (const float*)d_in[18];
  const float* bn2s  = (const float*)d_in[19];
  const float* bn2b  = (const float*)d_in[20];
  const float* Wup1  = (const float*)d_in[21];
  const float* bup1  = (const float*)d_in[22];
  const float* Wup2  = (const float*)d_in[23];
  const float* bup2  = (const float*)d_in[24];
  const float* Wp    = (const float*)d_in[25];
  const float* bp    = (const float*)d_in[26];
  const float* Wd    = (const float*)d_in[27];
  const float* bd    = (const float*)d_in[28];
  float* y = (float*)d_out;

  float* w = (float*)d_ws;
  float* trig = w;  w += T_*B_*D_;
  float* hbuf = w;  w += T_*NH_*B_*D_;
  float* og   = w;  w += T_*NH_*B_*D_;
  float* itb  = w;  w += NH_*B_*T_;
  float* ftb  = w;  w += NH_*B_*T_;
  unsigned short* xinb = (unsigned short*)w;  w += (T_*B_*D_)/2;
  unsigned short* qkb  = (unsigned short*)w;  w += (NH_*TB_*D_)/2;
  unsigned short* Wqt  = (unsigned short*)w;  w += (NH_*D_*D_)/2;
  unsigned short* Wkt  = (unsigned short*)w;  w += (NH_*D_*D_)/2;
  unsigned short* Wst  = (unsigned short*)w;  w += (NH_*D_*D_)/2;
  unsigned short* Wvt  = (unsigned short*)w;  w += (NH_*D_*D_)/2;
  unsigned short* Wot  = (unsigned short*)w;  w += (NH_*D_*D_)/2;
  unsigned short* Wu1t = (unsigned short*)w;  w += (H_*D_)/2;
  unsigned short* Wu2t = (unsigned short*)w;  w += (H_*D_)/2;
  unsigned short* qob  = (unsigned short*)w;  w += (NH_*B_*T_*D_)/2;
  unsigned short* kob  = (unsigned short*)w;  w += (NH_*B_*T_*D_)/2;
  unsigned short* vot  = (unsigned short*)w;  w += (NH_*B_*T_*D_)/2;
  unsigned short* Wpt  = (unsigned short*)w;  w += (NH_*D_*D_)/2;
  unsigned short* Wdt  = (unsigned short*)w;  w += (D_*H_)/2;

  k_prep <<<816, 256, 0, stream>>>(Wq, Wk, Wsk, Wv, Wo, Wup1, Wup2, Wp, Wd,
                                   Wqt, Wkt, Wst, Wvt, Wot, Wu1t, Wu2t, Wpt, Wdt);
  k_upcg <<<64, 256, 0, stream>>>(x, bn1s, bn1b, Wu1t, Wu2t, bup1, bup2, ck, cb,
                                  Wi, bi, Wf, bf, xinb, qkb, trig, itb, ftb);
  k_gemm5<<<320, 256, 0, stream>>>(qkb, xinb, Wqt, Wkt, Wst, Wvt, Wot,
                                   bq, bk, bsk, bv, bo, qob, kob, vot, hbuf, og);
  k_attn2<<<NH_*B_*4, 256, 0, stream>>>(qob, kob, vot, og, itb, ftb, hbuf);
  k_tail3b<<<16, 512, 0, stream>>>(hbuf, bn2s, bn2b, Wpt, bp, trig, Wdt, bd, x, y);
}

// Round 8
// 158.844 us; speedup vs baseline: 1.0365x; 1.0365x over previous
//
#include <hip/hip_runtime.h>
#include <hip/hip_bf16.h>

#define T_ 64
#define B_ 8
#define H_ 128
#define NH_ 4
#define D_ 256
#define TB_ 512          // T_*B_
#define EPS_ 1e-5f

typedef short bf16x8 __attribute__((ext_vector_type(8)));
typedef float f32x4 __attribute__((ext_vector_type(4)));

__device__ __forceinline__ float silu_(float x){ return x / (1.0f + __expf(-x)); }
__device__ __forceinline__ float sigm_(float x){ return 1.0f / (1.0f + __expf(-x)); }
__device__ __forceinline__ unsigned short tobf_(float f){
  unsigned u = __float_as_uint(f);
  u += 0x7FFF + ((u >> 16) & 1);          // round-to-nearest-even
  return (unsigned short)(u >> 16);
}
// A-fragment-linear address, element (m,k) of [M x 256] bf16 matrix (K=256)
__device__ __forceinline__ int afrag_(int m, int k){
  return (((m >> 4)*8 + (k >> 5))*64 + ((k >> 3)&3)*16 + (m & 15))*8 + (k & 7);
}
// generalized for K=1024 (32 kb per m-tile)
__device__ __forceinline__ int afrag1024_(int m, int k){
  return (((m >> 4)*32 + (k >> 5))*64 + ((k >> 3)&3)*16 + (m & 15))*8 + (k & 7);
}

// ---------------- K1: weight conversions only ----------------
// 0..639: Wq/Wk/Ws/Wv/Wo B-frag | 640..671: Wup1/2 B-frag K=128
// 672..799: Wpoll B-frag K=1024 | 800..815: Wdown B-frag K=256
__global__ __launch_bounds__(256) void k_prep(
    const float* __restrict__ Wq, const float* __restrict__ Wk, const float* __restrict__ Ws,
    const float* __restrict__ Wv, const float* __restrict__ Wo,
    const float* __restrict__ Wup1, const float* __restrict__ Wup2,
    const float* __restrict__ Wp, const float* __restrict__ Wd,
    unsigned short* __restrict__ Wqt, unsigned short* __restrict__ Wkt,
    unsigned short* __restrict__ Wst, unsigned short* __restrict__ Wvt,
    unsigned short* __restrict__ Wot,
    unsigned short* __restrict__ Wu1t, unsigned short* __restrict__ Wu2t,
    unsigned short* __restrict__ Wpt, unsigned short* __restrict__ Wdt){
  int bid = blockIdx.x;
  int tid = threadIdx.x;
  if (bid < 640){
    int sub = bid & 31;
    int h   = (bid >> 5) & 3;
    int mat = bid >> 7;
    const float* Win; unsigned short* Wout;
    switch (mat){
      case 0: Win = Wq; Wout = Wqt; break;
      case 1: Win = Wk; Wout = Wkt; break;
      case 2: Win = Ws; Wout = Wst; break;
      case 3: Win = Wv; Wout = Wvt; break;
      default: Win = Wo; Wout = Wot; break;
    }
    Win  += h * (D_*D_);
    Wout += h * (D_*D_);
    int gid = sub*256 + tid;
    int combo = gid >> 6;                // nt*8 + kb
    int l = gid & 63;
    int lm = l & 15, lq = l >> 4;
    int nt = combo >> 3, kb = combo & 7;
    int n = nt*16 + lm;
    int k0 = kb*32 + lq*8;
    bf16x8 v;
    #pragma unroll
    for (int j = 0; j < 8; j++) v[j] = (short)tobf_(Win[(k0+j)*D_ + n]);
    *(bf16x8*)(Wout + (combo*64 + l)*8) = v;
  } else if (bid < 672){
    int idx = bid - 640;
    const float* Win = (idx < 16) ? Wup1 : Wup2;
    unsigned short* Wout = (idx < 16) ? Wu1t : Wu2t;
    int sub = idx & 15;
    int gid = sub*256 + tid;             // [0,4096)
    int combo = gid >> 6;                // nt*4 + kb  (K=128)
    int l = gid & 63;
    int lm = l & 15, lq = l >> 4;
    int nt = combo >> 2, kb = combo & 3;
    int n = nt*16 + lm;
    int k0 = kb*32 + lq*8;
    bf16x8 v;
    #pragma unroll
    for (int j = 0; j < 8; j++) v[j] = (short)tobf_(Win[(k0+j)*D_ + n]);
    *(bf16x8*)(Wout + (combo*64 + l)*8) = v;
  } else if (bid < 800){
    // Wpoll [1024 x 256] -> B-frag K=1024
    int gid = (bid - 672)*256 + tid;     // [0, 32768)
    int combo = gid >> 6;                // nt*32 + kb
    int l = gid & 63;
    int lm = l & 15, lq = l >> 4;
    int nt = combo >> 5, kb = combo & 31;
    int n = nt*16 + lm;
    int k0 = kb*32 + lq*8;
    bf16x8 v;
    #pragma unroll
    for (int j = 0; j < 8; j++) v[j] = (short)tobf_(Wp[(k0+j)*D_ + n]);
    *(bf16x8*)(Wpt + (combo*64 + l)*8) = v;
  } else {
    // Wdown [256 x 128] -> B-frag K=256
    int gid = (bid - 800)*256 + tid;     // [0, 4096)
    int combo = gid >> 6;                // nt*8 + kb
    int l = gid & 63;
    int lm = l & 15, lq = l >> 4;
    int nt = combo >> 3, kb = combo & 7;
    int n = nt*16 + lm;
    int k0 = kb*32 + lq*8;
    bf16x8 v;
    #pragma unroll
    for (int j = 0; j < 8; j++) v[j] = (short)tobf_(Wd[(k0+j)*H_ + n]);
    *(bf16x8*)(Wdt + (combo*64 + l)*8) = v;
  }
}

// ---------------- K2: bn1 (fused) + up-proj MFMA + conv/gates (mat0) / trig (mat1) ----------------
// grid 64: mat = bid>>5, rt = bid&31 (16 rows = 2 t)
__global__ __launch_bounds__(256) void k_upcg(
    const float* __restrict__ x, const float* __restrict__ bn1s, const float* __restrict__ bn1b,
    const unsigned short* __restrict__ Wu1t, const unsigned short* __restrict__ Wu2t,
    const float* __restrict__ bup1, const float* __restrict__ bup2,
    const float* __restrict__ ck, const float* __restrict__ cb,
    const float* __restrict__ Wi, const float* __restrict__ bi,
    const float* __restrict__ Wf, const float* __restrict__ bfv,
    unsigned short* __restrict__ xinb, unsigned short* __restrict__ qkb,
    float* __restrict__ trig, float* __restrict__ itb, float* __restrict__ ftb){
  __shared__ float xs[16][257];
  __shared__ unsigned short uf[2048];     // u bf16 A-frag (16 x 128), 4 KB
  int bid = blockIdx.x;
  int mat = bid >> 5, rt = bid & 31;
  int tid = threadIdx.x;
  int w = tid >> 6, l = tid & 63, lm = l & 15, lq = l >> 4;
  // ---- bn1 in-block: thread = (t_local, hf); rows rt*16+m, m = t_local*8+b ----
  {
    int tl = tid >> 7, hf = tid & 127;
    int t = rt*2 + tl;
    const float* xp = x + t*(B_*H_) + hf;
    float v0[8]; float mu = 0.f;
    #pragma unroll
    for (int b = 0; b < 8; b++){ v0[b] = xp[b*H_]; mu += v0[b]; }
    mu *= 0.125f;
    float var = 0.f;
    #pragma unroll
    for (int b = 0; b < 8; b++){ float dd = v0[b]-mu; var += dd*dd; }
    var *= 0.125f;
    float sc = (1.0f/sqrtf(var + EPS_)) * bn1s[hf];
    float bs = bn1b[hf];
    // A-frag (K=128): addr = ((k>>5)*64 + ((k>>3)&3)*16 + m)*8 + (k&7)
    int base = ((hf >> 5)*64 + ((hf >> 3)&3)*16)*8 + (hf & 7);
    #pragma unroll
    for (int b = 0; b < 8; b++){
      int m = tl*8 + b;
      uf[base + m*8] = tobf_((v0[b]-mu)*sc + bs);
    }
  }
  __syncthreads();
  const unsigned short* Bt = (mat == 0) ? Wu1t : Wu2t;
  f32x4 acc[4];
  #pragma unroll
  for (int nt = 0; nt < 4; nt++) acc[nt] = (f32x4){0.f,0.f,0.f,0.f};
  const unsigned short* Bp = Bt + l*8;
  #pragma unroll
  for (int kb = 0; kb < 4; kb++){
    bf16x8 a = *(const bf16x8*)(uf + (kb*64 + l)*8);
    #pragma unroll
    for (int nt = 0; nt < 4; nt++){
      bf16x8 bfr = *(const bf16x8*)(Bp + (((w*4+nt)*4 + kb) << 9));
      acc[nt] = __builtin_amdgcn_mfma_f32_16x16x32_bf16(a, bfr, acc[nt], 0, 0, 0);
    }
  }
  const float* bias = (mat == 0) ? bup1 : bup2;
  #pragma unroll
  for (int nt = 0; nt < 4; nt++){
    #pragma unroll
    for (int r = 0; r < 4; r++){
      int m = lq*4 + r;
      int row = rt*16 + m;
      int e = w*64 + nt*16 + lm;
      float vv = acc[nt][r] + bias[e];
      if (mat == 1){
        trig[row*D_ + e] = silu_(vv);
      } else {
        xinb[afrag_(row, e)] = tobf_(vv);
        xs[m][e] = vv;
      }
    }
  }
  if (mat == 0){
    __syncthreads();
    int d = tid;
    #pragma unroll 4
    for (int m = 0; m < 16; m++){
      float x0  = xs[m][d];
      float xm1 = (d >= 1)   ? xs[m][d-1] : 0.f;
      float xp1 = (d <= 254) ? xs[m][d+1] : 0.f;
      float xp2 = (d <= 253) ? xs[m][d+2] : 0.f;
      int rowg = rt*16 + m;
      int fa = afrag_(rowg, d);
      #pragma unroll
      for (int h = 0; h < NH_; h++){
        float a2 = cb[h];
        a2 = fmaf(xm1, ck[0*NH_+h], a2);
        a2 = fmaf(x0,  ck[1*NH_+h], a2);
        a2 = fmaf(xp1, ck[2*NH_+h], a2);
        a2 = fmaf(xp2, ck[3*NH_+h], a2);
        qkb[h*(TB_*D_) + fa] = tobf_(silu_(a2));
      }
    }
    int dot = tid >> 2, l4 = tid & 3;
    int h = dot >> 4, m = dot & 15;
    float ai = 0.f, af = 0.f;
    const float* wi = Wi + h*D_;
    const float* wf = Wf + h*D_;
    #pragma unroll 8
    for (int jj = 0; jj < 64; jj++){
      int k = l4*64 + jj;
      float xv = xs[m][k];
      ai = fmaf(xv, wi[k], ai);
      af = fmaf(xv, wf[k], af);
    }
    ai += __shfl_down(ai, 1); af += __shfl_down(af, 1);
    ai += __shfl_down(ai, 2); af += __shfl_down(af, 2);
    if (l4 == 0){
      int rowg = rt*16 + m;
      int t = rowg >> 3, b = rowg & 7;
      itb[(h*B_ + b)*T_ + t] = ai + bi[h];
      ftb[(h*B_ + b)*T_ + t] = af + bfv[h];
    }
  }
}

// ---------------- K3: per-head 5-matmul MFMA GEMM; frag-layout epilogues for attn ----------------
__global__ __launch_bounds__(256) void k_gemm5(
    const unsigned short* __restrict__ qkb, const unsigned short* __restrict__ xinb,
    const unsigned short* __restrict__ Wqt, const unsigned short* __restrict__ Wkt,
    const unsigned short* __restrict__ Wst, const unsigned short* __restrict__ Wvt,
    const unsigned short* __restrict__ Wot,
    const float* __restrict__ bq, const float* __restrict__ bk, const float* __restrict__ bsk,
    const float* __restrict__ bv, const float* __restrict__ bo,
    unsigned short* __restrict__ qob, unsigned short* __restrict__ kob,
    unsigned short* __restrict__ vot,
    float* __restrict__ hb, float* __restrict__ og){
  int bid = blockIdx.x;
  int rt  = bid & 15;
  int h   = (bid >> 4) & 3;
  int mat = bid >> 6;                    // 0=q 1=k 2=skip 3=v 4=og
  int tid = threadIdx.x;
  int w = tid >> 6, l = tid & 63;
  int lm = l & 15, lq = l >> 4;
  int r0 = rt * 32;
  const unsigned short* A = (mat < 3) ? (qkb + h*(TB_*D_)) : xinb;
  const unsigned short* Bt;
  const float* bias;
  switch (mat){
    case 0: Bt = Wqt; bias = bq;  break;
    case 1: Bt = Wkt; bias = bk;  break;
    case 2: Bt = Wst; bias = bsk; break;
    case 3: Bt = Wvt; bias = bv;  break;
    default: Bt = Wot; bias = bo; break;
  }
  Bt += h*(D_*D_);
  f32x4 acc[2][4];
  #pragma unroll
  for (int mt = 0; mt < 2; mt++)
    #pragma unroll
    for (int nt = 0; nt < 4; nt++) acc[mt][nt] = (f32x4){0.f,0.f,0.f,0.f};
  const unsigned short* Ap = A + l*8;
  const unsigned short* Bp = Bt + l*8;
  #pragma unroll
  for (int kc = 0; kc < 8; kc++){
    bf16x8 a0 = *(const bf16x8*)(Ap + ((rt*16      + kc) << 9));
    bf16x8 a1 = *(const bf16x8*)(Ap + ((rt*16 + 8  + kc) << 9));
    bf16x8 b0 = *(const bf16x8*)(Bp + (((w*4+0)*8 + kc) << 9));
    bf16x8 b1 = *(const bf16x8*)(Bp + (((w*4+1)*8 + kc) << 9));
    bf16x8 b2 = *(const bf16x8*)(Bp + (((w*4+2)*8 + kc) << 9));
    bf16x8 b3 = *(const bf16x8*)(Bp + (((w*4+3)*8 + kc) << 9));
    acc[0][0] = __builtin_amdgcn_mfma_f32_16x16x32_bf16(a0, b0, acc[0][0], 0, 0, 0);
    acc[0][1] = __builtin_amdgcn_mfma_f32_16x16x32_bf16(a0, b1, acc[0][1], 0, 0, 0);
    acc[0][2] = __builtin_amdgcn_mfma_f32_16x16x32_bf16(a0, b2, acc[0][2], 0, 0, 0);
    acc[0][3] = __builtin_amdgcn_mfma_f32_16x16x32_bf16(a0, b3, acc[0][3], 0, 0, 0);
    acc[1][0] = __builtin_amdgcn_mfma_f32_16x16x32_bf16(a1, b0, acc[1][0], 0, 0, 0);
    acc[1][1] = __builtin_amdgcn_mfma_f32_16x16x32_bf16(a1, b1, acc[1][1], 0, 0, 0);
    acc[1][2] = __builtin_amdgcn_mfma_f32_16x16x32_bf16(a1, b2, acc[1][2], 0, 0, 0);
    acc[1][3] = __builtin_amdgcn_mfma_f32_16x16x32_bf16(a1, b3, acc[1][3], 0, 0, 0);
  }
  float bval[4];
  #pragma unroll
  for (int nt = 0; nt < 4; nt++) bval[nt] = bias[h*D_ + w*64 + nt*16 + lm];
  #pragma unroll
  for (int mt = 0; mt < 2; mt++){
    #pragma unroll
    for (int r = 0; r < 4; r++){
      int row = r0 + mt*16 + lq*4 + r;
      int t = row >> 3, b = row & 7;
      #pragma unroll
      for (int nt = 0; nt < 4; nt++){
        int e = w*64 + nt*16 + lm;
        float vv = acc[mt][nt][r] + bval[nt];
        if (mat <= 1){
          if (mat == 1) vv *= 0.0625f;
          unsigned short* ob = (mat == 0) ? qob : kob;
          int mt2 = t >> 4, kb2 = e >> 5;
          int lane2 = ((e >> 3)&3)*16 + (t & 15);
          ob[(h*B_ + b)*16384 + ((mt2*8 + kb2)*64 + lane2)*8 + (e & 7)] = tobf_(vv);
        } else if (mat == 3){
          int nt3 = e >> 4, kb3 = t >> 5;
          int lane3 = ((t >> 3)&3)*16 + lm;
          vot[(h*B_ + b)*16384 + ((nt3*2 + kb3)*64 + lane3)*8 + (t & 7)] = tobf_(vv);
        } else {
          int obase = (((t*NH_ + h)*B_ + b) << 8) + e;
          if (mat == 4) og[obase] = sigm_(vv);
          else          hb[obase] = vv;        // skip term
        }
      }
    }
  }
}

// ---------------- K4: MFMA attention with fused gate scan ----------------
__global__ __launch_bounds__(256) void k_attn2(
    const unsigned short* __restrict__ qob, const unsigned short* __restrict__ kob,
    const unsigned short* __restrict__ vot, const float* __restrict__ og,
    const float* __restrict__ itb, const float* __restrict__ ftb,
    float* __restrict__ hb){
  __shared__ unsigned short Pf[1024];
  __shared__ float partial[4][16];
  __shared__ float scal[16];
  int bid = blockIdx.x;
  int hbx = bid >> 2, tq = bid & 3;
  int h = hbx >> 3, b = hbx & 7;
  int tid = threadIdx.x;
  int w = tid >> 6, l = tid & 63, lm = l & 15, lq = l >> 4;
  float F  = ftb[hbx*T_ + l];
  float it = itb[hbx*T_ + l];
  #pragma unroll
  for (int off = 1; off < 64; off <<= 1){
    float v2 = __shfl_up(F, off);
    if (l >= off) F += v2;
  }
  float ct = it - F;
  float G = ct;
  #pragma unroll
  for (int off = 1; off < 64; off <<= 1){
    float v2 = __shfl_up(G, off);
    if (l >= off) G = fmaxf(G, v2);
  }
  float rb = -fmaxf(0.f, G);
  const unsigned short* Aq = qob + hbx*16384 + l*8;
  const unsigned short* Bk = kob + hbx*16384 + l*8;
  f32x4 accs = (f32x4){0.f,0.f,0.f,0.f};
  #pragma unroll
  for (int kc = 0; kc < 8; kc++){
    bf16x8 a  = *(const bf16x8*)(Aq + ((tq*8 + kc) << 9));
    bf16x8 bb = *(const bf16x8*)(Bk + ((w*8  + kc) << 9));
    accs = __builtin_amdgcn_mfma_f32_16x16x32_bf16(a, bb, accs, 0, 0, 0);
  }
  int s = w*16 + lm;
  float ct_s = __shfl(ct, s);
  float p[4], ps[4];
  #pragma unroll
  for (int r = 0; r < 4; r++){
    int t = tq*16 + lq*4 + r;
    float rb_t = __shfl(rb, t);
    float pv = (s <= t) ? __expf(ct_s + rb_t) * accs[r] : 0.f;
    p[r] = pv; ps[r] = pv;
  }
  #pragma unroll
  for (int off = 1; off < 16; off <<= 1){
    #pragma unroll
    for (int r = 0; r < 4; r++) ps[r] += __shfl_xor(ps[r], off);
  }
  if (lm == 0){
    #pragma unroll
    for (int r = 0; r < 4; r++) partial[w][lq*4 + r] = ps[r];
  }
  {
    int kbP = w >> 1;
    int laneP = ((w*2 + (lm >> 3)) & 3)*16;
    int jP = lm & 7;
    #pragma unroll
    for (int r = 0; r < 4; r++){
      int m = lq*4 + r;
      Pf[(kbP*64 + laneP + m)*8 + jP] = tobf_(p[r]);
    }
  }
  __syncthreads();
  if (tid < 16){
    float sum = partial[0][tid] + partial[1][tid] + partial[2][tid] + partial[3][tid];
    scal[tid] = 1.0f / fmaxf(fabsf(sum), 1.0f);
  }
  bf16x8 pa0 = *(const bf16x8*)(Pf + l*8);
  bf16x8 pa1 = *(const bf16x8*)(Pf + 512 + l*8);
  const unsigned short* Bv = vot + hbx*16384 + l*8;
  f32x4 acco[4];
  #pragma unroll
  for (int nt = 0; nt < 4; nt++) acco[nt] = (f32x4){0.f,0.f,0.f,0.f};
  #pragma unroll
  for (int nt = 0; nt < 4; nt++){
    int nt3 = w*4 + nt;
    bf16x8 b0 = *(const bf16x8*)(Bv + (((nt3*2 + 0)) << 9));
    bf16x8 b1 = *(const bf16x8*)(Bv + (((nt3*2 + 1)) << 9));
    acco[nt] = __builtin_amdgcn_mfma_f32_16x16x32_bf16(pa0, b0, acco[nt], 0, 0, 0);
    acco[nt] = __builtin_amdgcn_mfma_f32_16x16x32_bf16(pa1, b1, acco[nt], 0, 0, 0);
  }
  __syncthreads();
  #pragma unroll
  for (int nt = 0; nt < 4; nt++){
    #pragma unroll
    for (int r = 0; r < 4; r++){
      int tl = lq*4 + r;
      int t = tq*16 + tl;
      int e = (w*4 + nt)*16 + lm;
      int idx = (((t*NH_ + h)*B_ + b) << 8) + e;
      hb[idx] += og[idx] * acco[nt][r] * scal[tl];
    }
  }
}

// ---------------- K5a: bn2 -> hob (bf16 A-frag, M=512, K=1024), LDS-coalesced ----------------
// grid 64 (one t per block), 256 threads
__global__ __launch_bounds__(256) void k_bn2f(
    const float* __restrict__ hbuf, const float* __restrict__ bn2s, const float* __restrict__ bn2b,
    unsigned short* __restrict__ hob){
  __shared__ __align__(16) float hs[32*D_];     // 32 KB, [i][d] stride 256
  int t = blockIdx.x;
  int tid = threadIdx.x;
  const float* hp = hbuf + (t*NH_*B_)*D_;
  #pragma unroll
  for (int i = 0; i < 8; i++){
    int idx = (tid + i*256)*4;
    *(float4*)&hs[idx] = *(const float4*)&hp[idx];
  }
  __syncthreads();
  int d = tid;
  float v[32]; float mu = 0.f;
  #pragma unroll
  for (int i = 0; i < 32; i++){ v[i] = hs[i*D_ + d]; mu += v[i]; }
  mu *= (1.0f/32.0f);
  float var = 0.f;
  #pragma unroll
  for (int i = 0; i < 32; i++){ float dd = v[i]-mu; var += dd*dd; }
  var *= (1.0f/32.0f);
  float sc = (1.0f/sqrtf(var + EPS_)) * bn2s[d];
  float bs = bn2b[d];
  #pragma unroll
  for (int i = 0; i < 32; i++){          // i = h*8 + b
    int hh = i >> 3, b = i & 7;
    int m = t*B_ + b;
    int k = hh*D_ + d;
    hob[afrag1024_(m, k)] = tobf_((v[i]-mu)*sc + bs);
  }
}

// ---------------- K5b: MFMA poll (K=1024, *trig) + down (K=256, +x) ----------------
// grid 16 (32-row tiles), block 512 = 8 waves
__global__ __launch_bounds__(512) void k_tail2(
    const unsigned short* __restrict__ hob, const unsigned short* __restrict__ Wpt,
    const float* __restrict__ bp, const float* __restrict__ trig,
    const unsigned short* __restrict__ Wdt, const float* __restrict__ bd,
    const float* __restrict__ x, float* __restrict__ y){
  __shared__ unsigned short zf[8192];     // z bf16 A-frag (32 x 256), 16 KB
  int rt = blockIdx.x;
  int tid = threadIdx.x;
  int w = tid >> 6, l = tid & 63, lm = l & 15, lq = l >> 4;
  f32x4 acc[2][2];
  #pragma unroll
  for (int mt = 0; mt < 2; mt++)
    #pragma unroll
    for (int nt = 0; nt < 2; nt++) acc[mt][nt] = (f32x4){0.f,0.f,0.f,0.f};
  const unsigned short* Ap = hob + l*8;
  const unsigned short* Bp = Wpt + l*8;
  #pragma unroll 4
  for (int kc = 0; kc < 32; kc++){
    bf16x8 a0 = *(const bf16x8*)(Ap + (((rt*2+0)*32 + kc) << 9));
    bf16x8 a1 = *(const bf16x8*)(Ap + (((rt*2+1)*32 + kc) << 9));
    bf16x8 b0 = *(const bf16x8*)(Bp + (((w*2+0)*32 + kc) << 9));
    bf16x8 b1 = *(const bf16x8*)(Bp + (((w*2+1)*32 + kc) << 9));
    acc[0][0] = __builtin_amdgcn_mfma_f32_16x16x32_bf16(a0, b0, acc[0][0], 0, 0, 0);
    acc[0][1] = __builtin_amdgcn_mfma_f32_16x16x32_bf16(a0, b1, acc[0][1], 0, 0, 0);
    acc[1][0] = __builtin_amdgcn_mfma_f32_16x16x32_bf16(a1, b0, acc[1][0], 0, 0, 0);
    acc[1][1] = __builtin_amdgcn_mfma_f32_16x16x32_bf16(a1, b1, acc[1][1], 0, 0, 0);
  }
  #pragma unroll
  for (int mt = 0; mt < 2; mt++){
    #pragma unroll
    for (int nt = 0; nt < 2; nt++){
      int e = w*32 + nt*16 + lm;
      float bpe = bp[e];
      #pragma unroll
      for (int r = 0; r < 4; r++){
        int ml = mt*16 + lq*4 + r;
        int row = rt*32 + ml;
        float z = (acc[mt][nt][r] + bpe) * trig[row*D_ + e];
        zf[afrag_(ml, e)] = tobf_(z);
      }
    }
  }
  __syncthreads();
  f32x4 acc2[2];
  acc2[0] = (f32x4){0.f,0.f,0.f,0.f};
  acc2[1] = (f32x4){0.f,0.f,0.f,0.f};
  const unsigned short* Bdp = Wdt + l*8;
  #pragma unroll
  for (int kc = 0; kc < 8; kc++){
    bf16x8 a0 = *(const bf16x8*)(zf + ((0*8 + kc) << 9) + l*8);
    bf16x8 a1 = *(const bf16x8*)(zf + ((1*8 + kc) << 9) + l*8);
    bf16x8 bb = *(const bf16x8*)(Bdp + ((w*8 + kc) << 9));
    acc2[0] = __builtin_amdgcn_mfma_f32_16x16x32_bf16(a0, bb, acc2[0], 0, 0, 0);
    acc2[1] = __builtin_amdgcn_mfma_f32_16x16x32_bf16(a1, bb, acc2[1], 0, 0, 0);
  }
  int hh = w*16 + lm;
  float bde = bd[hh];
  #pragma unroll
  for (int mt = 0; mt < 2; mt++){
    #pragma unroll
    for (int r = 0; r < 4; r++){
      int row = rt*32 + mt*16 + lq*4 + r;
      y[row*H_ + hh] = acc2[mt][r] + bde + x[row*H_ + hh];
    }
  }
}

extern "C" void kernel_launch(void* const* d_in, const int* in_sizes, int n_in,
                              void* d_out, int out_size, void* d_ws, size_t ws_size,
                              hipStream_t stream){
  const float* x     = (const float*)d_in[0];
  const float* Wq    = (const float*)d_in[1];
  const float* bq    = (const float*)d_in[2];
  const float* Wk    = (const float*)d_in[3];
  const float* bk    = (const float*)d_in[4];
  const float* Wv    = (const float*)d_in[5];
  const float* bv    = (const float*)d_in[6];
  const float* ck    = (const float*)d_in[7];
  const float* cb    = (const float*)d_in[8];
  const float* Wi    = (const float*)d_in[9];
  const float* bi    = (const float*)d_in[10];
  const float* Wf    = (const float*)d_in[11];
  const float* bf    = (const float*)d_in[12];
  const float* Wo    = (const float*)d_in[13];
  const float* bo    = (const float*)d_in[14];
  const float* Wsk   = (const float*)d_in[15];
  const float* bsk   = (const float*)d_in[16];
  const float* bn1s  = (const float*)d_in[17];
  const float* bn1b  = (const float*)d_in[18];
  const float* bn2s  = (const float*)d_in[19];
  const float* bn2b  = (const float*)d_in[20];
  const float* Wup1  = (const float*)d_in[21];
  const float* bup1  = (const float*)d_in[22];
  const float* Wup2  = (const float*)d_in[23];
  const float* bup2  = (const float*)d_in[24];
  const float* Wp    = (const float*)d_in[25];
  const float* bp    = (const float*)d_in[26];
  const float* Wd    = (const float*)d_in[27];
  const float* bd    = (const float*)d_in[28];
  float* y = (float*)d_out;

  float* w = (float*)d_ws;
  float* trig = w;  w += T_*B_*D_;
  float* hbuf = w;  w += T_*NH_*B_*D_;
  float* og   = w;  w += T_*NH_*B_*D_;
  float* itb  = w;  w += NH_*B_*T_;
  float* ftb  = w;  w += NH_*B_*T_;
  unsigned short* xinb = (unsigned short*)w;  w += (T_*B_*D_)/2;
  unsigned short* qkb  = (unsigned short*)w;  w += (NH_*TB_*D_)/2;
  unsigned short* Wqt  = (unsigned short*)w;  w += (NH_*D_*D_)/2;
  unsigned short* Wkt  = (unsigned short*)w;  w += (NH_*D_*D_)/2;
  unsigned short* Wst  = (unsigned short*)w;  w += (NH_*D_*D_)/2;
  unsigned short* Wvt  = (unsigned short*)w;  w += (NH_*D_*D_)/2;
  unsigned short* Wot  = (unsigned short*)w;  w += (NH_*D_*D_)/2;
  unsigned short* Wu1t = (unsigned short*)w;  w += (H_*D_)/2;
  unsigned short* Wu2t = (unsigned short*)w;  w += (H_*D_)/2;
  unsigned short* qob  = (unsigned short*)w;  w += (NH_*B_*T_*D_)/2;
  unsigned short* kob  = (unsigned short*)w;  w += (NH_*B_*T_*D_)/2;
  unsigned short* vot  = (unsigned short*)w;  w += (NH_*B_*T_*D_)/2;
  unsigned short* hob  = (unsigned short*)w;  w += (TB_*NH_*D_)/2;
  unsigned short* Wpt  = (unsigned short*)w;  w += (NH_*D_*D_)/2;
  unsigned short* Wdt  = (unsigned short*)w;  w += (D_*H_)/2;

  k_prep <<<816, 256, 0, stream>>>(Wq, Wk, Wsk, Wv, Wo, Wup1, Wup2, Wp, Wd,
                                   Wqt, Wkt, Wst, Wvt, Wot, Wu1t, Wu2t, Wpt, Wdt);
  k_upcg <<<64, 256, 0, stream>>>(x, bn1s, bn1b, Wu1t, Wu2t, bup1, bup2, ck, cb,
                                  Wi, bi, Wf, bf, xinb, qkb, trig, itb, ftb);
  k_gemm5<<<320, 256, 0, stream>>>(qkb, xinb, Wqt, Wkt, Wst, Wvt, Wot,
                                   bq, bk, bsk, bv, bo, qob, kob, vot, hbuf, og);
  k_attn2<<<NH_*B_*4, 256, 0, stream>>>(qob, kob, vot, og, itb, ftb, hbuf);
  k_bn2f <<<T_, 256, 0, stream>>>(hbuf, bn2s, bn2b, hob);
  k_tail2<<<16, 512, 0, stream>>>(hob, Wpt, bp, trig, Wdt, bd, x, y);
}